// Round 15
// baseline (171.082 us; speedup 1.0000x reference)
//
#include <hip/hip_runtime.h>
#include <hip/hip_bf16.h>

typedef __bf16 bf16;
typedef __bf16 bf16x4 __attribute__((ext_vector_type(4)));
typedef __bf16 bf16x8 __attribute__((ext_vector_type(8)));
typedef float  f32x4  __attribute__((ext_vector_type(4)));

#define D_MODEL 1024
#define S_LEN   2048
#define BATCH   2
#define NH      16
#define HD      64
#define NX ((size_t)BATCH * S_LEN * D_MODEL)   // 4,194,304 elements

// async global->LDS, 16B per lane; LDS dest is wave-uniform base + lane*16
__device__ inline void gl_lds16(const bf16* g, bf16* l) {
    __builtin_amdgcn_global_load_lds(
        (const __attribute__((address_space(1))) void*)g,
        (__attribute__((address_space(3))) void*)l, 16, 0, 0);
}

// ---------------------------------------------------------------------------
// Fused conversion: blocks [0,2048) convert X f32->bf16 contiguous;
// blocks [2048,2816) transpose-convert W f32 [k][n] -> Wt bf16 [z*1024+n][k].
// ---------------------------------------------------------------------------
__global__ __launch_bounds__(256) void cvt_all(
    const float* __restrict__ x,
    const float* __restrict__ Wq, const float* __restrict__ Wk,
    const float* __restrict__ Wv,
    bf16* __restrict__ xb, bf16* __restrict__ Wt)
{
    if (blockIdx.x < 2048) {
        const size_t base = ((size_t)blockIdx.x * 256 + threadIdx.x) * 8;
        const float4 a = *(const float4*)(x + base);
        const float4 b = *(const float4*)(x + base + 4);
        bf16x8 o;
        o[0] = (bf16)a.x; o[1] = (bf16)a.y; o[2] = (bf16)a.z; o[3] = (bf16)a.w;
        o[4] = (bf16)b.x; o[5] = (bf16)b.y; o[6] = (bf16)b.z; o[7] = (bf16)b.w;
        *(bf16x8*)(xb + base) = o;
        return;
    }
    const int id = blockIdx.x - 2048;            // 768 tile-blocks
    const int z = id / 256, tid = id % 256;      // 16x16 tiles of 64x64
    const int k0 = (tid >> 4) * 64, n0 = (tid & 15) * 64;
    const float* W = (z == 0) ? Wq : (z == 1) ? Wk : Wv;

    __shared__ bf16 tile[64 * 72];
    const int r16 = threadIdx.x >> 4, c4 = (threadIdx.x & 15) << 2;

#pragma unroll
    for (int rr = 0; rr < 4; ++rr) {
        const int row = rr * 16 + r16;
        const float4 v = *(const float4*)(W + (size_t)(k0 + row) * D_MODEL + n0 + c4);
        bf16x4 o; o[0] = (bf16)v.x; o[1] = (bf16)v.y; o[2] = (bf16)v.z; o[3] = (bf16)v.w;
        *(bf16x4*)(tile + row * 72 + c4) = o;
    }
    __syncthreads();
#pragma unroll
    for (int rr = 0; rr < 4; ++rr) {
        const int row = rr * 16 + r16;
        bf16x4 o;
#pragma unroll
        for (int j = 0; j < 4; ++j) o[j] = tile[(c4 + j) * 72 + row];
        *(bf16x4*)(Wt + (size_t)(z * D_MODEL + n0 + row) * D_MODEL + k0 + c4) = o;
    }
}

// ---------------------------------------------------------------------------
// m97-class GEMM with XCD-aware swizzle: id%8 (=XCD by dispatch round-robin)
// selects a 3-n-tile band so each XCD's L2 holds its Wt band (0.75 MB);
// Xb streams from LLC once per XCD. C = Xb @ Wt^T + bias; Q pre-scaled 1/8.
// ---------------------------------------------------------------------------
__global__ __launch_bounds__(256) void gemm_bt(
    const bf16* __restrict__ Xb, const bf16* __restrict__ Wt,
    const float* __restrict__ bq, const float* __restrict__ bk,
    const float* __restrict__ bv, bf16* __restrict__ QKV)
{
    const int id  = blockIdx.y * gridDim.x + blockIdx.x;   // x fastest
    const int xcd = id & 7, rem = id >> 3;
    const int ntile = xcd * 3 + (rem % 3), mtile = rem / 3;
    const int n0 = ntile * 128, m0 = mtile * 128;
    const int z  = n0 >> 10;
    const float* bias = (z == 0) ? bq : (z == 1) ? bk : bv;
    const float scale = (z == 0) ? 0.125f : 1.0f;
    bf16* C = QKV + (size_t)z * NX;
    const int ncol0 = n0 & 1023;

    __shared__ bf16 As[128 * 32];
    __shared__ bf16 Bs[128 * 32];

    const int t = threadIdx.x, wave = t >> 6, lane = t & 63;
    const int wm = wave >> 1, wn = wave & 1;
    const int col = lane & 15, quad = lane >> 4;
    const int srow = t >> 2, sc8 = (t & 3) << 3;

    f32x4 acc[4][4] = {};

    for (int k0 = 0; k0 < D_MODEL; k0 += 32) {
        gl_lds16(Xb + (size_t)(m0 + srow) * D_MODEL + k0 + sc8,      As + wave * 512);
        gl_lds16(Xb + (size_t)(m0 + 64 + srow) * D_MODEL + k0 + sc8, As + 2048 + wave * 512);
        gl_lds16(Wt + (size_t)(n0 + srow) * D_MODEL + k0 + sc8,      Bs + wave * 512);
        gl_lds16(Wt + (size_t)(n0 + 64 + srow) * D_MODEL + k0 + sc8, Bs + 2048 + wave * 512);
        __syncthreads();

        bf16x8 a[4], b[4];
#pragma unroll
        for (int mt = 0; mt < 4; ++mt)
            a[mt] = *(const bf16x8*)(As + (wm * 64 + mt * 16 + col) * 32 + quad * 8);
#pragma unroll
        for (int nt = 0; nt < 4; ++nt)
            b[nt] = *(const bf16x8*)(Bs + (wn * 64 + nt * 16 + col) * 32 + quad * 8);
#pragma unroll
        for (int mt = 0; mt < 4; ++mt)
#pragma unroll
            for (int nt = 0; nt < 4; ++nt)
                acc[mt][nt] = __builtin_amdgcn_mfma_f32_16x16x32_bf16(a[mt], b[nt], acc[mt][nt], 0, 0, 0);
        __syncthreads();
    }

#pragma unroll
    for (int nt = 0; nt < 4; ++nt) {
        const int cgw = ncol0 + wn * 64 + nt * 16 + col;
        const float bsv = bias[cgw];
#pragma unroll
        for (int mt = 0; mt < 4; ++mt)
#pragma unroll
            for (int i = 0; i < 4; ++i) {
                const int rg = m0 + wm * 64 + mt * 16 + quad * 4 + i;
                C[(size_t)rg * D_MODEL + cgw] = (bf16)((acc[mt][nt][i] + bsv) * scale);
            }
    }
}

// ---------------------------------------------------------------------------
// Block-sparse flash attention. 64-key chunks, no-max single-pass softmax.
// K fragments loaded DIRECTLY from global (L2-resident; per-lane b128 loads,
// no staging, no barrier dependency). V transposed via double-buffered LDS:
// exactly 1 barrier per chunk. LDS 27.6 KB -> 5 blocks/CU. Output f32.
// ---------------------------------------------------------------------------
__global__ __launch_bounds__(256) void sparse_attn64(
    const bf16* __restrict__ Q, const bf16* __restrict__ Kv,
    const bf16* __restrict__ Vv, const float* __restrict__ kpm,
    float* __restrict__ out)
{
    const int w = (gridDim.x - 1) - blockIdx.x;   // longest windows first
    const int h = blockIdx.y, b = blockIdx.z;
    const int t = threadIdx.x, wavei = t >> 6, lane = t & 63;
    const int col = lane & 15, quad = lane >> 4;
    const int qb = 4 * w + wavei;

    __shared__ bf16 VtS[2][64 * 72];   // [d][kj]  stride 72
    __shared__ bf16 Ps[4][16 * 72];    // per-wave [qi][kj]

    const size_t qrow = ((size_t)(b * S_LEN + qb * 16 + col)) * D_MODEL + h * HD;
    const bf16x8 aq0 = *(const bf16x8*)(Q + qrow + quad * 8);
    const bf16x8 aq1 = *(const bf16x8*)(Q + qrow + 32 + quad * 8);

    f32x4 o[4] = {};
    float lacc[4] = {0.f, 0.f, 0.f, 0.f};

    const int nGlob = (w + 3) >> 2;
    const int niter = nGlob + 1;

    // V staging: thread = key pair (2p2, 2p2+1), d-range dg8..+7
    const int p2 = t & 31, dg8 = (t >> 5) << 3;
    const int key0 = 2 * p2, vg = key0 >> 4, vr = key0 & 15;

    auto kb_of = [&](int it, int g) -> int {
        if (it == nGlob) return 4 * w + g;
        const int j = 4 * it + g;
        return (j < w) ? (4 * j + 3) : 3;
    };

    bf16x8 rv0, rv1;
    {   // prologue: stage V chunk 0 into buffer 0
        const size_t vrow = ((size_t)(b * S_LEN + kb_of(0, vg) * 16 + vr)) * D_MODEL + h * HD + dg8;
        rv0 = *(const bf16x8*)(Vv + vrow);
        rv1 = *(const bf16x8*)(Vv + vrow + D_MODEL);
#pragma unroll
        for (int j = 0; j < 8; ++j) {
            bf16 pr[2] = { rv0[j], rv1[j] };
            *(unsigned int*)(VtS[0] + (dg8 + j) * 72 + key0) = *(unsigned int*)pr;
        }
    }

    for (int it = 0; it < niter; ++it) {
        __syncthreads();    // V chunk `it` visible; prev PV reads done
        const int cur = it & 1, nxt = cur ^ 1;
        const bool more = (it + 1 < niter);
        if (more) {   // prefetch next V chunk into registers
            const size_t vrow = ((size_t)(b * S_LEN + kb_of(it + 1, vg) * 16 + vr)) * D_MODEL + h * HD + dg8;
            rv0 = *(const bf16x8*)(Vv + vrow);
            rv1 = *(const bf16x8*)(Vv + vrow + D_MODEL);
        }
        const bf16* Vt = VtS[cur];

        // ---- S = Q K^T, K fragments direct from global (L2) ----
        f32x4 s[4];
        float mval[4];
        bool  val[4];
#pragma unroll
        for (int g = 0; g < 4; ++g) {
            int kb;
            if (it == nGlob) { kb = 4 * w + g; val[g] = (g <= wavei); }
            else { const int j = 4 * it + g; val[g] = (j < w); kb = val[g] ? (4 * j + 3) : 3; }
            mval[g] = kpm[b * S_LEN + kb * 16 + col];
            const bf16* kp = Kv + ((size_t)(b * S_LEN + kb * 16 + col)) * D_MODEL + h * HD;
            const bf16x8 bk0 = *(const bf16x8*)(kp + quad * 8);
            const bf16x8 bk1 = *(const bf16x8*)(kp + 32 + quad * 8);
            f32x4 z = {};
            z = __builtin_amdgcn_mfma_f32_16x16x32_bf16(aq0, bk0, z, 0, 0, 0);
            s[g] = __builtin_amdgcn_mfma_f32_16x16x32_bf16(aq1, bk1, z, 0, 0, 0);
        }

        // ---- p = exp(s + mask); order-free accumulation, no max ----
#pragma unroll
        for (int i = 0; i < 4; ++i) {
#pragma unroll
            for (int g = 0; g < 4; ++g) {
                const float si = val[g] ? (s[g][i] + mval[g]) : -1e30f;
                const float pv = __expf(si);
                lacc[i] += pv;
                Ps[wavei][(quad * 4 + i) * 72 + g * 16 + col] = (bf16)pv;
            }
        }

        // ---- O += P V : full K-depth 64 ----
        const bf16x8 aP0 = *(const bf16x8*)(Ps[wavei] + col * 72 + quad * 8);
        const bf16x8 aP1 = *(const bf16x8*)(Ps[wavei] + col * 72 + 32 + quad * 8);
#pragma unroll
        for (int nt = 0; nt < 4; ++nt) {
            const bf16x8 b0 = *(const bf16x8*)(Vt + (nt * 16 + col) * 72 + quad * 8);
            const bf16x8 b1 = *(const bf16x8*)(Vt + (nt * 16 + col) * 72 + 32 + quad * 8);
            o[nt] = __builtin_amdgcn_mfma_f32_16x16x32_bf16(aP0, b0, o[nt], 0, 0, 0);
            o[nt] = __builtin_amdgcn_mfma_f32_16x16x32_bf16(aP1, b1, o[nt], 0, 0, 0);
        }

        if (more) {   // stage next V into the other buffer (no barrier)
#pragma unroll
            for (int j = 0; j < 8; ++j) {
                bf16 pr[2] = { rv0[j], rv1[j] };
                *(unsigned int*)(VtS[nxt] + (dg8 + j) * 72 + key0) = *(unsigned int*)pr;
            }
        }
    }

    // ---- deferred row-sum reduction + f32 output ----
#pragma unroll
    for (int i = 0; i < 4; ++i) {
        float rs = lacc[i];
        rs += __shfl_xor(rs, 1);
        rs += __shfl_xor(rs, 2);
        rs += __shfl_xor(rs, 4);
        rs += __shfl_xor(rs, 8);
        const float inv = 1.0f / rs;
        const int rg = b * S_LEN + qb * 16 + quad * 4 + i;
#pragma unroll
        for (int nt = 0; nt < 4; ++nt)
            out[(size_t)rg * D_MODEL + h * HD + nt * 16 + col] = o[nt][i] * inv;
    }
}

// ---------------------------------------------------------------------------
extern "C" void kernel_launch(void* const* d_in, const int* in_sizes, int n_in,
                              void* d_out, int out_size, void* d_ws, size_t ws_size,
                              hipStream_t stream)
{
    const float* x = nullptr; const float* kpm = nullptr;
    const float* Wp[3] = {nullptr, nullptr, nullptr};
    const float* bp[3] = {nullptr, nullptr, nullptr};
    int wn = 0, bn = 0;
    for (int i = 0; i < n_in; ++i) {
        const float* p = (const float*)d_in[i];
        const long s = in_sizes[i];
        if (s == (long)NX)            x = p;
        else if (s == BATCH * S_LEN)  kpm = p;
        else if (s == D_MODEL * D_MODEL && wn < 3) Wp[wn++] = p;
        else if (s == D_MODEL && bn < 3)           bp[bn++] = p;
    }

    // ws (24 MB): [Q | K | V] bf16.  d_out doubles as [Xb 8MB | Wt 6MB] scratch.
    bf16* Qb = (bf16*)d_ws;
    bf16* Kb = Qb + NX;
    bf16* Vb = Kb + NX;
    bf16* Xb = (bf16*)d_out;
    bf16* Wt = Xb + NX;
    float* outp = (float*)d_out;

    cvt_all<<<2048 + 768, 256, 0, stream>>>(x, Wp[0], Wp[1], Wp[2], Xb, Wt);

    gemm_bt<<<dim3(24, 32), 256, 0, stream>>>(Xb, Wt, bp[0], bp[1], bp[2], Qb);

    sparse_attn64<<<dim3(S_LEN / 64, NH, BATCH), 256, 0, stream>>>(
        Qb, Kb, Vb, kpm, outp);
}

// Round 16
// 167.318 us; speedup vs baseline: 1.0225x; 1.0225x over previous
//
#include <hip/hip_runtime.h>
#include <hip/hip_bf16.h>

typedef __bf16 bf16;
typedef __bf16 bf16x4 __attribute__((ext_vector_type(4)));
typedef __bf16 bf16x8 __attribute__((ext_vector_type(8)));
typedef float  f32x4  __attribute__((ext_vector_type(4)));

#define D_MODEL 1024
#define S_LEN   2048
#define BATCH   2
#define NH      16
#define HD      64
#define NX ((size_t)BATCH * S_LEN * D_MODEL)   // 4,194,304 elements
#define NROWS (BATCH * S_LEN)                  // 4096

// async global->LDS, 16B per lane; LDS dest is wave-uniform base + lane*16
__device__ inline void gl_lds16(const bf16* g, bf16* l) {
    __builtin_amdgcn_global_load_lds(
        (const __attribute__((address_space(1))) void*)g,
        (__attribute__((address_space(3))) void*)l, 16, 0, 0);
}

// ---------------------------------------------------------------------------
// Fused conversion: blocks [0,2048) convert X f32->bf16 contiguous;
// blocks [2048,2816) transpose-convert W f32 [k][n] -> Wt bf16 [z*1024+n][k].
// ---------------------------------------------------------------------------
__global__ __launch_bounds__(256) void cvt_all(
    const float* __restrict__ x,
    const float* __restrict__ Wq, const float* __restrict__ Wk,
    const float* __restrict__ Wv,
    bf16* __restrict__ xb, bf16* __restrict__ Wt)
{
    if (blockIdx.x < 2048) {
        const size_t base = ((size_t)blockIdx.x * 256 + threadIdx.x) * 8;
        const float4 a = *(const float4*)(x + base);
        const float4 b = *(const float4*)(x + base + 4);
        bf16x8 o;
        o[0] = (bf16)a.x; o[1] = (bf16)a.y; o[2] = (bf16)a.z; o[3] = (bf16)a.w;
        o[4] = (bf16)b.x; o[5] = (bf16)b.y; o[6] = (bf16)b.z; o[7] = (bf16)b.w;
        *(bf16x8*)(xb + base) = o;
        return;
    }
    const int id = blockIdx.x - 2048;
    const int z = id / 256, tid = id % 256;
    const int k0 = (tid >> 4) * 64, n0 = (tid & 15) * 64;
    const float* W = (z == 0) ? Wq : (z == 1) ? Wk : Wv;

    __shared__ bf16 tile[64 * 72];
    const int r16 = threadIdx.x >> 4, c4 = (threadIdx.x & 15) << 2;

#pragma unroll
    for (int rr = 0; rr < 4; ++rr) {
        const int row = rr * 16 + r16;
        const float4 v = *(const float4*)(W + (size_t)(k0 + row) * D_MODEL + n0 + c4);
        bf16x4 o; o[0] = (bf16)v.x; o[1] = (bf16)v.y; o[2] = (bf16)v.z; o[3] = (bf16)v.w;
        *(bf16x4*)(tile + row * 72 + c4) = o;
    }
    __syncthreads();
#pragma unroll
    for (int rr = 0; rr < 4; ++rr) {
        const int row = rr * 16 + r16;
        bf16x4 o;
#pragma unroll
        for (int j = 0; j < 4; ++j) o[j] = tile[(c4 + j) * 72 + row];
        *(bf16x4*)(Wt + (size_t)(z * D_MODEL + n0 + row) * D_MODEL + k0 + c4) = o;
    }
}

// ---------------------------------------------------------------------------
// Zero-init O_acc (NX f32) + L (NROWS*16 f32), contiguous range.
// ---------------------------------------------------------------------------
__global__ __launch_bounds__(256) void zero_acc(float* __restrict__ p)
{
    const size_t i = ((size_t)blockIdx.x * 256 + threadIdx.x) * 4;
    *(float4*)(p + i) = make_float4(0.f, 0.f, 0.f, 0.f);
}

// ---------------------------------------------------------------------------
// m97-class GEMM (unchanged from r15): C = Xb @ Wt^T + bias; Q pre-scaled 1/8.
// ---------------------------------------------------------------------------
__global__ __launch_bounds__(256) void gemm_bt(
    const bf16* __restrict__ Xb, const bf16* __restrict__ Wt,
    const float* __restrict__ bq, const float* __restrict__ bk,
    const float* __restrict__ bv, bf16* __restrict__ QKV)
{
    const int id  = blockIdx.y * gridDim.x + blockIdx.x;
    const int xcd = id & 7, rem = id >> 3;
    const int ntile = xcd * 3 + (rem % 3), mtile = rem / 3;
    const int n0 = ntile * 128, m0 = mtile * 128;
    const int z  = n0 >> 10;
    const float* bias = (z == 0) ? bq : (z == 1) ? bk : bv;
    const float scale = (z == 0) ? 0.125f : 1.0f;
    bf16* C = QKV + (size_t)z * NX;
    const int ncol0 = n0 & 1023;

    __shared__ bf16 As[128 * 32];
    __shared__ bf16 Bs[128 * 32];

    const int t = threadIdx.x, wave = t >> 6, lane = t & 63;
    const int wm = wave >> 1, wn = wave & 1;
    const int col = lane & 15, quad = lane >> 4;
    const int srow = t >> 2, sc8 = (t & 3) << 3;

    f32x4 acc[4][4] = {};

    for (int k0 = 0; k0 < D_MODEL; k0 += 32) {
        gl_lds16(Xb + (size_t)(m0 + srow) * D_MODEL + k0 + sc8,      As + wave * 512);
        gl_lds16(Xb + (size_t)(m0 + 64 + srow) * D_MODEL + k0 + sc8, As + 2048 + wave * 512);
        gl_lds16(Wt + (size_t)(n0 + srow) * D_MODEL + k0 + sc8,      Bs + wave * 512);
        gl_lds16(Wt + (size_t)(n0 + 64 + srow) * D_MODEL + k0 + sc8, Bs + 2048 + wave * 512);
        __syncthreads();

        bf16x8 a[4], b[4];
#pragma unroll
        for (int mt = 0; mt < 4; ++mt)
            a[mt] = *(const bf16x8*)(As + (wm * 64 + mt * 16 + col) * 32 + quad * 8);
#pragma unroll
        for (int nt = 0; nt < 4; ++nt)
            b[nt] = *(const bf16x8*)(Bs + (wn * 64 + nt * 16 + col) * 32 + quad * 8);
#pragma unroll
        for (int mt = 0; mt < 4; ++mt)
#pragma unroll
            for (int nt = 0; nt < 4; ++nt)
                acc[mt][nt] = __builtin_amdgcn_mfma_f32_16x16x32_bf16(a[mt], b[nt], acc[mt][nt], 0, 0, 0);
        __syncthreads();
    }

#pragma unroll
    for (int nt = 0; nt < 4; ++nt) {
        const int cgw = ncol0 + wn * 64 + nt * 16 + col;
        const float bsv = bias[cgw];
#pragma unroll
        for (int mt = 0; mt < 4; ++mt)
#pragma unroll
            for (int i = 0; i < 4; ++i) {
                const int rg = m0 + wm * 64 + mt * 16 + quad * 4 + i;
                C[(size_t)rg * D_MODEL + cgw] = (bf16)((acc[mt][nt][i] + bsv) * scale);
            }
    }
}

// ---------------------------------------------------------------------------
// Block-sparse flash attention, PARTITIONED: each block processes <=4 of a
// window's 64-key chunks (r14 chunk body: K+V dbuf LDS staging, register
// prefetch, 1 barrier/chunk, no-max softmax). Parts combine linearly via
// device-scope f32 atomicAdd into O_acc and L (valid because no-max softmax
// partial sums are order-free). Longest windows dispatch first.
// ---------------------------------------------------------------------------
__global__ __launch_bounds__(256) void sparse_attn_part(
    const bf16* __restrict__ Q, const bf16* __restrict__ Kv,
    const bf16* __restrict__ Vv, const float* __restrict__ kpm,
    float* __restrict__ Oacc, float* __restrict__ L)
{
    const int hb = blockIdx.y, h = hb >> 1, b = hb & 1;
    const int t = threadIdx.x, wavei = t >> 6, lane = t & 63;
    const int col = lane & 15, quad = lane >> 4;

    // map blockIdx.x -> (window w, chunk range [c0,c1)); w descends with x
    int w = 0, c0 = 0, c1 = 1;
    {
        int x = blockIdx.x, acc = 0;
        for (int wd = 0; wd < 32; ++wd) {
            const int wc = 31 - wd;
            const int ni = ((wc + 3) >> 2) + 1;
            const int np = (ni + 3) >> 2;
            if (x < acc + np) {
                w = wc;
                const int p = x - acc;
                c0 = p * 4;
                c1 = (c0 + 4 < ni) ? (c0 + 4) : ni;
                break;
            }
            acc += np;
        }
    }
    const int qb = 4 * w + wavei;
    const int nGlob = (w + 3) >> 2;

    __shared__ bf16 KbS[2][64 * 72];   // [kj][d]  stride 72
    __shared__ bf16 VtS[2][64 * 72];   // [d][kj]  stride 72
    __shared__ bf16 Ps[4][16 * 72];    // per-wave [qi][kj]

    const size_t qrow = ((size_t)(b * S_LEN + qb * 16 + col)) * D_MODEL + h * HD;
    const bf16x8 aq0 = *(const bf16x8*)(Q + qrow + quad * 8);
    const bf16x8 aq1 = *(const bf16x8*)(Q + qrow + 32 + quad * 8);

    f32x4 o[4] = {};
    float lacc[4] = {0.f, 0.f, 0.f, 0.f};

    // K staging: thread = row srow (0..63), d-range sd16..+15
    const int srow = t >> 2, sd16 = (t & 3) << 4;
    const int sg = srow >> 4, sr = srow & 15;
    // V staging: thread = key pair (2p2, 2p2+1), d-range dg8..+7
    const int p2 = t & 31, dg8 = (t >> 5) << 3;
    const int key0 = 2 * p2, vg = key0 >> 4, vr = key0 & 15;

    auto kb_of = [&](int it, int g) -> int {
        if (it == nGlob) return 4 * w + g;
        const int j = 4 * it + g;
        return (j < w) ? (4 * j + 3) : 3;
    };

    bf16x8 rk0, rk1, rv0, rv1;
    {   // prologue: load + stage chunk c0 into buffer (c0&1)
        const size_t krow = ((size_t)(b * S_LEN + kb_of(c0, sg) * 16 + sr)) * D_MODEL + h * HD + sd16;
        rk0 = *(const bf16x8*)(Kv + krow);
        rk1 = *(const bf16x8*)(Kv + krow + 8);
        const size_t vrow = ((size_t)(b * S_LEN + kb_of(c0, vg) * 16 + vr)) * D_MODEL + h * HD + dg8;
        rv0 = *(const bf16x8*)(Vv + vrow);
        rv1 = *(const bf16x8*)(Vv + vrow + D_MODEL);
        bf16* Kb = KbS[c0 & 1];
        bf16* Vt = VtS[c0 & 1];
        *(bf16x8*)(Kb + srow * 72 + sd16)     = rk0;
        *(bf16x8*)(Kb + srow * 72 + sd16 + 8) = rk1;
#pragma unroll
        for (int j = 0; j < 8; ++j) {
            bf16 pr[2] = { rv0[j], rv1[j] };
            *(unsigned int*)(Vt + (dg8 + j) * 72 + key0) = *(unsigned int*)pr;
        }
    }

    for (int it = c0; it < c1; ++it) {
        __syncthreads();
        const int cur = it & 1, nxt = cur ^ 1;
        const bool more = (it + 1 < c1);
        if (more) {
            const size_t krow = ((size_t)(b * S_LEN + kb_of(it + 1, sg) * 16 + sr)) * D_MODEL + h * HD + sd16;
            rk0 = *(const bf16x8*)(Kv + krow);
            rk1 = *(const bf16x8*)(Kv + krow + 8);
            const size_t vrow = ((size_t)(b * S_LEN + kb_of(it + 1, vg) * 16 + vr)) * D_MODEL + h * HD + dg8;
            rv0 = *(const bf16x8*)(Vv + vrow);
            rv1 = *(const bf16x8*)(Vv + vrow + D_MODEL);
        }
        const bf16* Kb = KbS[cur];
        const bf16* Vt = VtS[cur];

        // ---- S = Q K^T over 64 keys ----
        f32x4 s[4];
        float mval[4];
        bool  val[4];
#pragma unroll
        for (int g = 0; g < 4; ++g) {
            int kb;
            if (it == nGlob) { kb = 4 * w + g; val[g] = (g <= wavei); }
            else { const int j = 4 * it + g; val[g] = (j < w); kb = val[g] ? (4 * j + 3) : 3; }
            mval[g] = kpm[b * S_LEN + kb * 16 + col];
            f32x4 z = {};
            const bf16x8 bk0 = *(const bf16x8*)(Kb + (g * 16 + col) * 72 + quad * 8);
            const bf16x8 bk1 = *(const bf16x8*)(Kb + (g * 16 + col) * 72 + 32 + quad * 8);
            z = __builtin_amdgcn_mfma_f32_16x16x32_bf16(aq0, bk0, z, 0, 0, 0);
            s[g] = __builtin_amdgcn_mfma_f32_16x16x32_bf16(aq1, bk1, z, 0, 0, 0);
        }

        // ---- p = exp(s + mask); order-free accumulation, no max ----
#pragma unroll
        for (int i = 0; i < 4; ++i) {
#pragma unroll
            for (int g = 0; g < 4; ++g) {
                const float si = val[g] ? (s[g][i] + mval[g]) : -1e30f;
                const float pv = __expf(si);
                lacc[i] += pv;
                Ps[wavei][(quad * 4 + i) * 72 + g * 16 + col] = (bf16)pv;
            }
        }

        // ---- O += P V : full K-depth 64 ----
        const bf16x8 aP0 = *(const bf16x8*)(Ps[wavei] + col * 72 + quad * 8);
        const bf16x8 aP1 = *(const bf16x8*)(Ps[wavei] + col * 72 + 32 + quad * 8);
#pragma unroll
        for (int nt = 0; nt < 4; ++nt) {
            const bf16x8 b0 = *(const bf16x8*)(Vt + (nt * 16 + col) * 72 + quad * 8);
            const bf16x8 b1 = *(const bf16x8*)(Vt + (nt * 16 + col) * 72 + 32 + quad * 8);
            o[nt] = __builtin_amdgcn_mfma_f32_16x16x32_bf16(aP0, b0, o[nt], 0, 0, 0);
            o[nt] = __builtin_amdgcn_mfma_f32_16x16x32_bf16(aP1, b1, o[nt], 0, 0, 0);
        }

        if (more) {
            bf16* KbN = KbS[nxt];
            bf16* VtN = VtS[nxt];
            *(bf16x8*)(KbN + srow * 72 + sd16)     = rk0;
            *(bf16x8*)(KbN + srow * 72 + sd16 + 8) = rk1;
#pragma unroll
            for (int j = 0; j < 8; ++j) {
                bf16 pr[2] = { rv0[j], rv1[j] };
                *(unsigned int*)(VtN + (dg8 + j) * 72 + key0) = *(unsigned int*)pr;
            }
        }
    }

    // ---- partial epilogue: atomic combine into O_acc and L ----
#pragma unroll
    for (int i = 0; i < 4; ++i) {
        float rs = lacc[i];
        rs += __shfl_xor(rs, 1);
        rs += __shfl_xor(rs, 2);
        rs += __shfl_xor(rs, 4);
        rs += __shfl_xor(rs, 8);
        const int rg = b * S_LEN + qb * 16 + quad * 4 + i;
        if (col == 0) atomicAdd(L + rg * NH + h, rs);
#pragma unroll
        for (int nt = 0; nt < 4; ++nt)
            atomicAdd(Oacc + (size_t)rg * D_MODEL + h * HD + nt * 16 + col, o[nt][i]);
    }
}

// ---------------------------------------------------------------------------
// Normalize: out = O_acc / L  (f32 output).
// ---------------------------------------------------------------------------
__global__ __launch_bounds__(256) void normalize_out(
    const float* __restrict__ Oacc, const float* __restrict__ L,
    float* __restrict__ out)
{
    const size_t i4 = ((size_t)blockIdx.x * 256 + threadIdx.x) * 4;
    const int rg = (int)(i4 >> 10);
    const int h  = ((int)i4 & 1023) >> 6;
    const float inv = 1.0f / L[rg * NH + h];
    float4 v = *(const float4*)(Oacc + i4);
    v.x *= inv; v.y *= inv; v.z *= inv; v.w *= inv;
    *(float4*)(out + i4) = v;
}

// ---------------------------------------------------------------------------
extern "C" void kernel_launch(void* const* d_in, const int* in_sizes, int n_in,
                              void* d_out, int out_size, void* d_ws, size_t ws_size,
                              hipStream_t stream)
{
    const float* x = nullptr; const float* kpm = nullptr;
    const float* Wp[3] = {nullptr, nullptr, nullptr};
    const float* bp[3] = {nullptr, nullptr, nullptr};
    int wn = 0, bn = 0;
    for (int i = 0; i < n_in; ++i) {
        const float* p = (const float*)d_in[i];
        const long s = in_sizes[i];
        if (s == (long)NX)            x = p;
        else if (s == BATCH * S_LEN)  kpm = p;
        else if (s == D_MODEL * D_MODEL && wn < 3) Wp[wn++] = p;
        else if (s == D_MODEL && bn < 3)           bp[bn++] = p;
    }

    // ws: [Q 8MB | K 8MB | V 8MB | O_acc 16MB | L 256KB]  (40.25 MB)
    bf16*  Qb   = (bf16*)d_ws;
    bf16*  Kb   = Qb + NX;
    bf16*  Vb   = Kb + NX;
    float* Oacc = (float*)(Vb + NX);
    // d_out doubles as pre-attention scratch: [Xb 8MB | Wt 6MB].
    bf16* Xb = (bf16*)d_out;
    bf16* Wt = Xb + NX;
    float* outp = (float*)d_out;

    cvt_all<<<2048 + 768, 256, 0, stream>>>(x, Wp[0], Wp[1], Wp[2], Xb, Wt);

    // zero O_acc + L (contiguous): (NX + NROWS*NH) floats = 4,259,840 -> 4160 blocks
    zero_acc<<<(int)((NX + (size_t)NROWS * NH) / 4 / 256), 256, 0, stream>>>(Oacc);

    gemm_bt<<<dim3(24, 32), 256, 0, stream>>>(Xb, Wt, bp[0], bp[1], bp[2], Qb);

    sparse_attn_part<<<dim3(54, NH * BATCH), 256, 0, stream>>>(
        Qb, Kb, Vb, kpm, Oacc, Oacc + NX);

    normalize_out<<<(int)(NX / 4 / 256), 256, 0, stream>>>(Oacc, Oacc + NX, outp);
}

// Round 17
// 165.891 us; speedup vs baseline: 1.0313x; 1.0086x over previous
//
#include <hip/hip_runtime.h>
#include <hip/hip_bf16.h>

typedef __bf16 bf16;
typedef __bf16 bf16x4 __attribute__((ext_vector_type(4)));
typedef __bf16 bf16x8 __attribute__((ext_vector_type(8)));
typedef float  f32x4  __attribute__((ext_vector_type(4)));

#define D_MODEL 1024
#define S_LEN   2048
#define BATCH   2
#define NH      16
#define HD      64
#define NX ((size_t)BATCH * S_LEN * D_MODEL)   // 4,194,304 elements
#define NROWS (BATCH * S_LEN)                  // 4096

// async global->LDS, 16B per lane; LDS dest is wave-uniform base + lane*16
__device__ inline void gl_lds16(const bf16* g, bf16* l) {
    __builtin_amdgcn_global_load_lds(
        (const __attribute__((address_space(1))) void*)g,
        (__attribute__((address_space(3))) void*)l, 16, 0, 0);
}

// ---------------------------------------------------------------------------
// Fused conversion: blocks [0,2048) convert X f32->bf16 contiguous;
// blocks [2048,2816) transpose-convert W f32 [k][n] -> Wt bf16 [z*1024+n][k].
// ---------------------------------------------------------------------------
__global__ __launch_bounds__(256) void cvt_all(
    const float* __restrict__ x,
    const float* __restrict__ Wq, const float* __restrict__ Wk,
    const float* __restrict__ Wv,
    bf16* __restrict__ xb, bf16* __restrict__ Wt)
{
    if (blockIdx.x < 2048) {
        const size_t base = ((size_t)blockIdx.x * 256 + threadIdx.x) * 8;
        const float4 a = *(const float4*)(x + base);
        const float4 b = *(const float4*)(x + base + 4);
        bf16x8 o;
        o[0] = (bf16)a.x; o[1] = (bf16)a.y; o[2] = (bf16)a.z; o[3] = (bf16)a.w;
        o[4] = (bf16)b.x; o[5] = (bf16)b.y; o[6] = (bf16)b.z; o[7] = (bf16)b.w;
        *(bf16x8*)(xb + base) = o;
        return;
    }
    const int id = blockIdx.x - 2048;
    const int z = id / 256, tid = id % 256;
    const int k0 = (tid >> 4) * 64, n0 = (tid & 15) * 64;
    const float* W = (z == 0) ? Wq : (z == 1) ? Wk : Wv;

    __shared__ bf16 tile[64 * 72];
    const int r16 = threadIdx.x >> 4, c4 = (threadIdx.x & 15) << 2;

#pragma unroll
    for (int rr = 0; rr < 4; ++rr) {
        const int row = rr * 16 + r16;
        const float4 v = *(const float4*)(W + (size_t)(k0 + row) * D_MODEL + n0 + c4);
        bf16x4 o; o[0] = (bf16)v.x; o[1] = (bf16)v.y; o[2] = (bf16)v.z; o[3] = (bf16)v.w;
        *(bf16x4*)(tile + row * 72 + c4) = o;
    }
    __syncthreads();
#pragma unroll
    for (int rr = 0; rr < 4; ++rr) {
        const int row = rr * 16 + r16;
        bf16x4 o;
#pragma unroll
        for (int j = 0; j < 4; ++j) o[j] = tile[(c4 + j) * 72 + row];
        *(bf16x4*)(Wt + (size_t)(z * D_MODEL + n0 + row) * D_MODEL + k0 + c4) = o;
    }
}

// ---------------------------------------------------------------------------
// Zero-init O_acc (NX f32) + L (NROWS*16 f32), contiguous range.
// ---------------------------------------------------------------------------
__global__ __launch_bounds__(256) void zero_acc(float* __restrict__ p)
{
    const size_t i = ((size_t)blockIdx.x * 256 + threadIdx.x) * 4;
    *(float4*)(p + i) = make_float4(0.f, 0.f, 0.f, 0.f);
}

// ---------------------------------------------------------------------------
// m97-class GEMM: C = Xb @ Wt^T + bias; Q pre-scaled 1/8. COALESCED epilogue:
// acc -> per-wave LDS transpose tile (stride 66, conflict-spread) -> bf16x8
// line stores (8 lanes x 16 B = full 128 B line per row). Fixes the r16
// counters: WRITE_SIZE 58 MB (2.4x ampl.) from 32 B scattered segments.
// ---------------------------------------------------------------------------
__global__ __launch_bounds__(256) void gemm_bt(
    const bf16* __restrict__ Xb, const bf16* __restrict__ Wt,
    const float* __restrict__ bq, const float* __restrict__ bk,
    const float* __restrict__ bv, bf16* __restrict__ QKV)
{
    const int id  = blockIdx.y * gridDim.x + blockIdx.x;
    const int xcd = id & 7, rem = id >> 3;
    const int ntile = xcd * 3 + (rem % 3), mtile = rem / 3;
    const int n0 = ntile * 128, m0 = mtile * 128;
    const int z  = n0 >> 10;
    const float* bias = (z == 0) ? bq : (z == 1) ? bk : bv;
    const float scale = (z == 0) ? 0.125f : 1.0f;
    bf16* C = QKV + (size_t)z * NX;
    const int ncol0 = n0 & 1023;

    __shared__ bf16 As[128 * 32];
    __shared__ bf16 Bs[128 * 32];
    __shared__ bf16 Es[4][16 * 66];   // per-wave epilogue transpose tile

    const int t = threadIdx.x, wave = t >> 6, lane = t & 63;
    const int wm = wave >> 1, wn = wave & 1;
    const int col = lane & 15, quad = lane >> 4;
    const int srow = t >> 2, sc8 = (t & 3) << 3;

    f32x4 acc[4][4] = {};

    for (int k0 = 0; k0 < D_MODEL; k0 += 32) {
        gl_lds16(Xb + (size_t)(m0 + srow) * D_MODEL + k0 + sc8,      As + wave * 512);
        gl_lds16(Xb + (size_t)(m0 + 64 + srow) * D_MODEL + k0 + sc8, As + 2048 + wave * 512);
        gl_lds16(Wt + (size_t)(n0 + srow) * D_MODEL + k0 + sc8,      Bs + wave * 512);
        gl_lds16(Wt + (size_t)(n0 + 64 + srow) * D_MODEL + k0 + sc8, Bs + 2048 + wave * 512);
        __syncthreads();

        bf16x8 a[4], b[4];
#pragma unroll
        for (int mt = 0; mt < 4; ++mt)
            a[mt] = *(const bf16x8*)(As + (wm * 64 + mt * 16 + col) * 32 + quad * 8);
#pragma unroll
        for (int nt = 0; nt < 4; ++nt)
            b[nt] = *(const bf16x8*)(Bs + (wn * 64 + nt * 16 + col) * 32 + quad * 8);
#pragma unroll
        for (int mt = 0; mt < 4; ++mt)
#pragma unroll
            for (int nt = 0; nt < 4; ++nt)
                acc[mt][nt] = __builtin_amdgcn_mfma_f32_16x16x32_bf16(a[mt], b[nt], acc[mt][nt], 0, 0, 0);
        __syncthreads();
    }

    // ---- coalesced epilogue: per-wave LDS transpose, then 128B line stores
    bf16* E = Es[wave];
    const int r8 = lane >> 3, c8 = (lane & 7) << 3;
#pragma unroll
    for (int mt = 0; mt < 4; ++mt) {
#pragma unroll
        for (int nt = 0; nt < 4; ++nt) {
            const float bsv = bias[ncol0 + wn * 64 + nt * 16 + col];
#pragma unroll
            for (int i = 0; i < 4; ++i)
                E[(quad * 4 + i) * 66 + nt * 16 + col] =
                    (bf16)((acc[mt][nt][i] + bsv) * scale);
        }
        // wave-synchronous LDS RAW (compiler inserts lgkmcnt waits)
#pragma unroll
        for (int ph = 0; ph < 2; ++ph) {
            const int row = ph * 8 + r8;
            const bf16x8 v = *(const bf16x8*)(E + row * 66 + c8);
            const int rg = m0 + wm * 64 + mt * 16 + row;
            *(bf16x8*)(C + (size_t)rg * D_MODEL + ncol0 + wn * 64 + c8) = v;
        }
    }
}

// ---------------------------------------------------------------------------
// Block-sparse flash attention, PARTITIONED (unchanged from r16): each block
// processes <=4 of a window's 64-key chunks; parts combine linearly via
// device-scope f32 atomicAdd into O_acc and L (no-max softmax partial sums
// are order-free). Longest windows dispatch first.
// ---------------------------------------------------------------------------
__global__ __launch_bounds__(256) void sparse_attn_part(
    const bf16* __restrict__ Q, const bf16* __restrict__ Kv,
    const bf16* __restrict__ Vv, const float* __restrict__ kpm,
    float* __restrict__ Oacc, float* __restrict__ L)
{
    const int hb = blockIdx.y, h = hb >> 1, b = hb & 1;
    const int t = threadIdx.x, wavei = t >> 6, lane = t & 63;
    const int col = lane & 15, quad = lane >> 4;

    int w = 0, c0 = 0, c1 = 1;
    {
        int x = blockIdx.x, acc = 0;
        for (int wd = 0; wd < 32; ++wd) {
            const int wc = 31 - wd;
            const int ni = ((wc + 3) >> 2) + 1;
            const int np = (ni + 3) >> 2;
            if (x < acc + np) {
                w = wc;
                const int p = x - acc;
                c0 = p * 4;
                c1 = (c0 + 4 < ni) ? (c0 + 4) : ni;
                break;
            }
            acc += np;
        }
    }
    const int qb = 4 * w + wavei;
    const int nGlob = (w + 3) >> 2;

    __shared__ bf16 KbS[2][64 * 72];
    __shared__ bf16 VtS[2][64 * 72];
    __shared__ bf16 Ps[4][16 * 72];

    const size_t qrow = ((size_t)(b * S_LEN + qb * 16 + col)) * D_MODEL + h * HD;
    const bf16x8 aq0 = *(const bf16x8*)(Q + qrow + quad * 8);
    const bf16x8 aq1 = *(const bf16x8*)(Q + qrow + 32 + quad * 8);

    f32x4 o[4] = {};
    float lacc[4] = {0.f, 0.f, 0.f, 0.f};

    const int srow = t >> 2, sd16 = (t & 3) << 4;
    const int sg = srow >> 4, sr = srow & 15;
    const int p2 = t & 31, dg8 = (t >> 5) << 3;
    const int key0 = 2 * p2, vg = key0 >> 4, vr = key0 & 15;

    auto kb_of = [&](int it, int g) -> int {
        if (it == nGlob) return 4 * w + g;
        const int j = 4 * it + g;
        return (j < w) ? (4 * j + 3) : 3;
    };

    bf16x8 rk0, rk1, rv0, rv1;
    {
        const size_t krow = ((size_t)(b * S_LEN + kb_of(c0, sg) * 16 + sr)) * D_MODEL + h * HD + sd16;
        rk0 = *(const bf16x8*)(Kv + krow);
        rk1 = *(const bf16x8*)(Kv + krow + 8);
        const size_t vrow = ((size_t)(b * S_LEN + kb_of(c0, vg) * 16 + vr)) * D_MODEL + h * HD + dg8;
        rv0 = *(const bf16x8*)(Vv + vrow);
        rv1 = *(const bf16x8*)(Vv + vrow + D_MODEL);
        bf16* Kb = KbS[c0 & 1];
        bf16* Vt = VtS[c0 & 1];
        *(bf16x8*)(Kb + srow * 72 + sd16)     = rk0;
        *(bf16x8*)(Kb + srow * 72 + sd16 + 8) = rk1;
#pragma unroll
        for (int j = 0; j < 8; ++j) {
            bf16 pr[2] = { rv0[j], rv1[j] };
            *(unsigned int*)(Vt + (dg8 + j) * 72 + key0) = *(unsigned int*)pr;
        }
    }

    for (int it = c0; it < c1; ++it) {
        __syncthreads();
        const int cur = it & 1, nxt = cur ^ 1;
        const bool more = (it + 1 < c1);
        if (more) {
            const size_t krow = ((size_t)(b * S_LEN + kb_of(it + 1, sg) * 16 + sr)) * D_MODEL + h * HD + sd16;
            rk0 = *(const bf16x8*)(Kv + krow);
            rk1 = *(const bf16x8*)(Kv + krow + 8);
            const size_t vrow = ((size_t)(b * S_LEN + kb_of(it + 1, vg) * 16 + vr)) * D_MODEL + h * HD + dg8;
            rv0 = *(const bf16x8*)(Vv + vrow);
            rv1 = *(const bf16x8*)(Vv + vrow + D_MODEL);
        }
        const bf16* Kb = KbS[cur];
        const bf16* Vt = VtS[cur];

        f32x4 s[4];
        float mval[4];
        bool  val[4];
#pragma unroll
        for (int g = 0; g < 4; ++g) {
            int kb;
            if (it == nGlob) { kb = 4 * w + g; val[g] = (g <= wavei); }
            else { const int j = 4 * it + g; val[g] = (j < w); kb = val[g] ? (4 * j + 3) : 3; }
            mval[g] = kpm[b * S_LEN + kb * 16 + col];
            f32x4 zz = {};
            const bf16x8 bk0 = *(const bf16x8*)(Kb + (g * 16 + col) * 72 + quad * 8);
            const bf16x8 bk1 = *(const bf16x8*)(Kb + (g * 16 + col) * 72 + 32 + quad * 8);
            zz = __builtin_amdgcn_mfma_f32_16x16x32_bf16(aq0, bk0, zz, 0, 0, 0);
            s[g] = __builtin_amdgcn_mfma_f32_16x16x32_bf16(aq1, bk1, zz, 0, 0, 0);
        }

#pragma unroll
        for (int i = 0; i < 4; ++i) {
#pragma unroll
            for (int g = 0; g < 4; ++g) {
                const float si = val[g] ? (s[g][i] + mval[g]) : -1e30f;
                const float pv = __expf(si);
                lacc[i] += pv;
                Ps[wavei][(quad * 4 + i) * 72 + g * 16 + col] = (bf16)pv;
            }
        }

        const bf16x8 aP0 = *(const bf16x8*)(Ps[wavei] + col * 72 + quad * 8);
        const bf16x8 aP1 = *(const bf16x8*)(Ps[wavei] + col * 72 + 32 + quad * 8);
#pragma unroll
        for (int nt = 0; nt < 4; ++nt) {
            const bf16x8 b0 = *(const bf16x8*)(Vt + (nt * 16 + col) * 72 + quad * 8);
            const bf16x8 b1 = *(const bf16x8*)(Vt + (nt * 16 + col) * 72 + 32 + quad * 8);
            o[nt] = __builtin_amdgcn_mfma_f32_16x16x32_bf16(aP0, b0, o[nt], 0, 0, 0);
            o[nt] = __builtin_amdgcn_mfma_f32_16x16x32_bf16(aP1, b1, o[nt], 0, 0, 0);
        }

        if (more) {
            bf16* KbN = KbS[nxt];
            bf16* VtN = VtS[nxt];
            *(bf16x8*)(KbN + srow * 72 + sd16)     = rk0;
            *(bf16x8*)(KbN + srow * 72 + sd16 + 8) = rk1;
#pragma unroll
            for (int j = 0; j < 8; ++j) {
                bf16 pr[2] = { rv0[j], rv1[j] };
                *(unsigned int*)(VtN + (dg8 + j) * 72 + key0) = *(unsigned int*)pr;
            }
        }
    }

#pragma unroll
    for (int i = 0; i < 4; ++i) {
        float rs = lacc[i];
        rs += __shfl_xor(rs, 1);
        rs += __shfl_xor(rs, 2);
        rs += __shfl_xor(rs, 4);
        rs += __shfl_xor(rs, 8);
        const int rg = b * S_LEN + qb * 16 + quad * 4 + i;
        if (col == 0) atomicAdd(L + rg * NH + h, rs);
#pragma unroll
        for (int nt = 0; nt < 4; ++nt)
            atomicAdd(Oacc + (size_t)rg * D_MODEL + h * HD + nt * 16 + col, o[nt][i]);
    }
}

// ---------------------------------------------------------------------------
// Normalize: out = O_acc / L  (f32 output).
// ---------------------------------------------------------------------------
__global__ __launch_bounds__(256) void normalize_out(
    const float* __restrict__ Oacc, const float* __restrict__ L,
    float* __restrict__ out)
{
    const size_t i4 = ((size_t)blockIdx.x * 256 + threadIdx.x) * 4;
    const int rg = (int)(i4 >> 10);
    const int h  = ((int)i4 & 1023) >> 6;
    const float inv = 1.0f / L[rg * NH + h];
    float4 v = *(const float4*)(Oacc + i4);
    v.x *= inv; v.y *= inv; v.z *= inv; v.w *= inv;
    *(float4*)(out + i4) = v;
}

// ---------------------------------------------------------------------------
extern "C" void kernel_launch(void* const* d_in, const int* in_sizes, int n_in,
                              void* d_out, int out_size, void* d_ws, size_t ws_size,
                              hipStream_t stream)
{
    const float* x = nullptr; const float* kpm = nullptr;
    const float* Wp[3] = {nullptr, nullptr, nullptr};
    const float* bp[3] = {nullptr, nullptr, nullptr};
    int wn = 0, bn = 0;
    for (int i = 0; i < n_in; ++i) {
        const float* p = (const float*)d_in[i];
        const long s = in_sizes[i];
        if (s == (long)NX)            x = p;
        else if (s == BATCH * S_LEN)  kpm = p;
        else if (s == D_MODEL * D_MODEL && wn < 3) Wp[wn++] = p;
        else if (s == D_MODEL && bn < 3)           bp[bn++] = p;
    }

    // ws: [Q 8MB | K 8MB | V 8MB | O_acc 16MB | L 256KB]
    bf16*  Qb   = (bf16*)d_ws;
    bf16*  Kb   = Qb + NX;
    bf16*  Vb   = Kb + NX;
    float* Oacc = (float*)(Vb + NX);
    // d_out doubles as pre-attention scratch: [Xb 8MB | Wt 6MB].
    bf16* Xb = (bf16*)d_out;
    bf16* Wt = Xb + NX;
    float* outp = (float*)d_out;

    cvt_all<<<2048 + 768, 256, 0, stream>>>(x, Wp[0], Wp[1], Wp[2], Xb, Wt);

    zero_acc<<<(int)((NX + (size_t)NROWS * NH) / 4 / 256), 256, 0, stream>>>(Oacc);

    gemm_bt<<<dim3(24, 32), 256, 0, stream>>>(Xb, Wt, bp[0], bp[1], bp[2], Qb);

    sparse_attn_part<<<dim3(54, NH * BATCH), 256, 0, stream>>>(
        Qb, Kb, Vb, kpm, Oacc, Oacc + NX);

    normalize_out<<<(int)(NX / 4 / 256), 256, 0, stream>>>(Oacc, Oacc + NX, outp);
}

// Round 18
// 160.623 us; speedup vs baseline: 1.0651x; 1.0328x over previous
//
#include <hip/hip_runtime.h>
#include <hip/hip_bf16.h>

typedef __bf16 bf16;
typedef __bf16 bf16x4 __attribute__((ext_vector_type(4)));
typedef __bf16 bf16x8 __attribute__((ext_vector_type(8)));
typedef float  f32x4  __attribute__((ext_vector_type(4)));

#define D_MODEL 1024
#define S_LEN   2048
#define BATCH   2
#define NH      16
#define HD      64
#define NX ((size_t)BATCH * S_LEN * D_MODEL)   // 4,194,304 elements
#define NROWS (BATCH * S_LEN)                  // 4096
#define MPROW0 832                             // first multi-part row (qb>=52)
#define MPROWS 1216                            // multi-part rows per batch

// async global->LDS, 16B per lane; LDS dest is wave-uniform base + lane*16
__device__ inline void gl_lds16(const bf16* g, bf16* l) {
    __builtin_amdgcn_global_load_lds(
        (const __attribute__((address_space(1))) void*)g,
        (__attribute__((address_space(3))) void*)l, 16, 0, 0);
}

// ---------------------------------------------------------------------------
// Fused conversion + accumulator zeroing:
//  blocks [0,2048)      : X f32 -> bf16 contiguous
//  blocks [2048,2816)   : W f32 [k][n] -> Wt bf16 [z*1024+n][k]
//  blocks [2816,5248)   : zero Oacc multi-part rows (832..2047 per b)
//  blocks [5248,5312)   : zero L
// ---------------------------------------------------------------------------
__global__ __launch_bounds__(256) void cvt_all(
    const float* __restrict__ x,
    const float* __restrict__ Wq, const float* __restrict__ Wk,
    const float* __restrict__ Wv,
    bf16* __restrict__ xb, bf16* __restrict__ Wt,
    float* __restrict__ Oacc, float* __restrict__ L)
{
    if (blockIdx.x < 2048) {
        const size_t base = ((size_t)blockIdx.x * 256 + threadIdx.x) * 8;
        const float4 a = *(const float4*)(x + base);
        const float4 b = *(const float4*)(x + base + 4);
        bf16x8 o;
        o[0] = (bf16)a.x; o[1] = (bf16)a.y; o[2] = (bf16)a.z; o[3] = (bf16)a.w;
        o[4] = (bf16)b.x; o[5] = (bf16)b.y; o[6] = (bf16)b.z; o[7] = (bf16)b.w;
        *(bf16x8*)(xb + base) = o;
        return;
    }
    if (blockIdx.x < 2816) {
        const int id = blockIdx.x - 2048;
        const int z = id / 256, tid = id % 256;
        const int k0 = (tid >> 4) * 64, n0 = (tid & 15) * 64;
        const float* W = (z == 0) ? Wq : (z == 1) ? Wk : Wv;

        __shared__ bf16 tile[64 * 72];
        const int r16 = threadIdx.x >> 4, c4 = (threadIdx.x & 15) << 2;

#pragma unroll
        for (int rr = 0; rr < 4; ++rr) {
            const int row = rr * 16 + r16;
            const float4 v = *(const float4*)(W + (size_t)(k0 + row) * D_MODEL + n0 + c4);
            bf16x4 o; o[0] = (bf16)v.x; o[1] = (bf16)v.y; o[2] = (bf16)v.z; o[3] = (bf16)v.w;
            *(bf16x4*)(tile + row * 72 + c4) = o;
        }
        __syncthreads();
#pragma unroll
        for (int rr = 0; rr < 4; ++rr) {
            const int row = rr * 16 + r16;
            bf16x4 o;
#pragma unroll
            for (int j = 0; j < 4; ++j) o[j] = tile[(c4 + j) * 72 + row];
            *(bf16x4*)(Wt + (size_t)(z * D_MODEL + n0 + row) * D_MODEL + k0 + c4) = o;
        }
        return;
    }
    if (blockIdx.x < 5248) {   // zero Oacc multi-part region
        const int g   = (blockIdx.x - 2816) * 256 + threadIdx.x;
        const int b   = g / (MPROWS * 256);
        const int rem = g % (MPROWS * 256);
        const int row = MPROW0 + (rem >> 8);
        const int c4  = (rem & 255) << 2;
        const size_t off = (size_t)(b * S_LEN + row) * D_MODEL + c4;
        *(float4*)(Oacc + off) = make_float4(0.f, 0.f, 0.f, 0.f);
        return;
    }
    {   // zero L (NROWS*NH floats)
        const int g = (blockIdx.x - 5248) * 256 + threadIdx.x;
        *(float4*)(L + (size_t)g * 4) = make_float4(0.f, 0.f, 0.f, 0.f);
    }
}

// ---------------------------------------------------------------------------
// m97-class GEMM: C = Xb @ Wt^T + bias; Q pre-scaled 1/8. Coalesced epilogue
// via per-wave LDS transpose (r17, verified).
// ---------------------------------------------------------------------------
__global__ __launch_bounds__(256) void gemm_bt(
    const bf16* __restrict__ Xb, const bf16* __restrict__ Wt,
    const float* __restrict__ bq, const float* __restrict__ bk,
    const float* __restrict__ bv, bf16* __restrict__ QKV)
{
    const int id  = blockIdx.y * gridDim.x + blockIdx.x;
    const int xcd = id & 7, rem = id >> 3;
    const int ntile = xcd * 3 + (rem % 3), mtile = rem / 3;
    const int n0 = ntile * 128, m0 = mtile * 128;
    const int z  = n0 >> 10;
    const float* bias = (z == 0) ? bq : (z == 1) ? bk : bv;
    const float scale = (z == 0) ? 0.125f : 1.0f;
    bf16* C = QKV + (size_t)z * NX;
    const int ncol0 = n0 & 1023;

    __shared__ bf16 As[128 * 32];
    __shared__ bf16 Bs[128 * 32];
    __shared__ bf16 Es[4][16 * 66];

    const int t = threadIdx.x, wave = t >> 6, lane = t & 63;
    const int wm = wave >> 1, wn = wave & 1;
    const int col = lane & 15, quad = lane >> 4;
    const int srow = t >> 2, sc8 = (t & 3) << 3;

    f32x4 acc[4][4] = {};

    for (int k0 = 0; k0 < D_MODEL; k0 += 32) {
        gl_lds16(Xb + (size_t)(m0 + srow) * D_MODEL + k0 + sc8,      As + wave * 512);
        gl_lds16(Xb + (size_t)(m0 + 64 + srow) * D_MODEL + k0 + sc8, As + 2048 + wave * 512);
        gl_lds16(Wt + (size_t)(n0 + srow) * D_MODEL + k0 + sc8,      Bs + wave * 512);
        gl_lds16(Wt + (size_t)(n0 + 64 + srow) * D_MODEL + k0 + sc8, Bs + 2048 + wave * 512);
        __syncthreads();

        bf16x8 a[4], b[4];
#pragma unroll
        for (int mt = 0; mt < 4; ++mt)
            a[mt] = *(const bf16x8*)(As + (wm * 64 + mt * 16 + col) * 32 + quad * 8);
#pragma unroll
        for (int nt = 0; nt < 4; ++nt)
            b[nt] = *(const bf16x8*)(Bs + (wn * 64 + nt * 16 + col) * 32 + quad * 8);
#pragma unroll
        for (int mt = 0; mt < 4; ++mt)
#pragma unroll
            for (int nt = 0; nt < 4; ++nt)
                acc[mt][nt] = __builtin_amdgcn_mfma_f32_16x16x32_bf16(a[mt], b[nt], acc[mt][nt], 0, 0, 0);
        __syncthreads();
    }

    bf16* E = Es[wave];
    const int r8 = lane >> 3, c8 = (lane & 7) << 3;
#pragma unroll
    for (int mt = 0; mt < 4; ++mt) {
#pragma unroll
        for (int nt = 0; nt < 4; ++nt) {
            const float bsv = bias[ncol0 + wn * 64 + nt * 16 + col];
#pragma unroll
            for (int i = 0; i < 4; ++i)
                E[(quad * 4 + i) * 66 + nt * 16 + col] =
                    (bf16)((acc[mt][nt][i] + bsv) * scale);
        }
#pragma unroll
        for (int ph = 0; ph < 2; ++ph) {
            const int row = ph * 8 + r8;
            const bf16x8 v = *(const bf16x8*)(E + row * 66 + c8);
            const int rg = m0 + wm * 64 + mt * 16 + row;
            *(bf16x8*)(C + (size_t)rg * D_MODEL + ncol0 + wn * 64 + c8) = v;
        }
    }
}

// ---------------------------------------------------------------------------
// Block-sparse flash attention, PARTITIONED. Single-part windows (w<=12)
// normalize in-register and write f32 out directly (no atomics, no second
// pass). Multi-part windows combine via device-scope atomicAdd (no-max
// softmax partial sums are order-free). Longest windows dispatch first.
// ---------------------------------------------------------------------------
__global__ __launch_bounds__(256) void sparse_attn_part(
    const bf16* __restrict__ Q, const bf16* __restrict__ Kv,
    const bf16* __restrict__ Vv, const float* __restrict__ kpm,
    float* __restrict__ Oacc, float* __restrict__ L,
    float* __restrict__ out)
{
    const int hb = blockIdx.y, h = hb >> 1, b = hb & 1;
    const int t = threadIdx.x, wavei = t >> 6, lane = t & 63;
    const int col = lane & 15, quad = lane >> 4;

    int w = 0, c0 = 0, c1 = 1;
    {
        int x = blockIdx.x, acc = 0;
        for (int wd = 0; wd < 32; ++wd) {
            const int wc = 31 - wd;
            const int ni = ((wc + 3) >> 2) + 1;
            const int np = (ni + 3) >> 2;
            if (x < acc + np) {
                w = wc;
                const int p = x - acc;
                c0 = p * 4;
                c1 = (c0 + 4 < ni) ? (c0 + 4) : ni;
                break;
            }
            acc += np;
        }
    }
    const int qb = 4 * w + wavei;
    const int nGlob = (w + 3) >> 2;
    const bool single = (w <= 12);   // one part covers the whole window

    __shared__ bf16 KbS[2][64 * 72];
    __shared__ bf16 VtS[2][64 * 72];
    __shared__ bf16 Ps[4][16 * 72];

    const size_t qrow = ((size_t)(b * S_LEN + qb * 16 + col)) * D_MODEL + h * HD;
    const bf16x8 aq0 = *(const bf16x8*)(Q + qrow + quad * 8);
    const bf16x8 aq1 = *(const bf16x8*)(Q + qrow + 32 + quad * 8);

    f32x4 o[4] = {};
    float lacc[4] = {0.f, 0.f, 0.f, 0.f};

    const int srow = t >> 2, sd16 = (t & 3) << 4;
    const int sg = srow >> 4, sr = srow & 15;
    const int p2 = t & 31, dg8 = (t >> 5) << 3;
    const int key0 = 2 * p2, vg = key0 >> 4, vr = key0 & 15;

    auto kb_of = [&](int it, int g) -> int {
        if (it == nGlob) return 4 * w + g;
        const int j = 4 * it + g;
        return (j < w) ? (4 * j + 3) : 3;
    };

    bf16x8 rk0, rk1, rv0, rv1;
    {
        const size_t krow = ((size_t)(b * S_LEN + kb_of(c0, sg) * 16 + sr)) * D_MODEL + h * HD + sd16;
        rk0 = *(const bf16x8*)(Kv + krow);
        rk1 = *(const bf16x8*)(Kv + krow + 8);
        const size_t vrow = ((size_t)(b * S_LEN + kb_of(c0, vg) * 16 + vr)) * D_MODEL + h * HD + dg8;
        rv0 = *(const bf16x8*)(Vv + vrow);
        rv1 = *(const bf16x8*)(Vv + vrow + D_MODEL);
        bf16* Kb = KbS[c0 & 1];
        bf16* Vt = VtS[c0 & 1];
        *(bf16x8*)(Kb + srow * 72 + sd16)     = rk0;
        *(bf16x8*)(Kb + srow * 72 + sd16 + 8) = rk1;
#pragma unroll
        for (int j = 0; j < 8; ++j) {
            bf16 pr[2] = { rv0[j], rv1[j] };
            *(unsigned int*)(Vt + (dg8 + j) * 72 + key0) = *(unsigned int*)pr;
        }
    }

    for (int it = c0; it < c1; ++it) {
        __syncthreads();
        const int cur = it & 1, nxt = cur ^ 1;
        const bool more = (it + 1 < c1);
        if (more) {
            const size_t krow = ((size_t)(b * S_LEN + kb_of(it + 1, sg) * 16 + sr)) * D_MODEL + h * HD + sd16;
            rk0 = *(const bf16x8*)(Kv + krow);
            rk1 = *(const bf16x8*)(Kv + krow + 8);
            const size_t vrow = ((size_t)(b * S_LEN + kb_of(it + 1, vg) * 16 + vr)) * D_MODEL + h * HD + dg8;
            rv0 = *(const bf16x8*)(Vv + vrow);
            rv1 = *(const bf16x8*)(Vv + vrow + D_MODEL);
        }
        const bf16* Kb = KbS[cur];
        const bf16* Vt = VtS[cur];

        f32x4 s[4];
        float mval[4];
        bool  val[4];
#pragma unroll
        for (int g = 0; g < 4; ++g) {
            int kb;
            if (it == nGlob) { kb = 4 * w + g; val[g] = (g <= wavei); }
            else { const int j = 4 * it + g; val[g] = (j < w); kb = val[g] ? (4 * j + 3) : 3; }
            mval[g] = kpm[b * S_LEN + kb * 16 + col];
            f32x4 zz = {};
            const bf16x8 bk0 = *(const bf16x8*)(Kb + (g * 16 + col) * 72 + quad * 8);
            const bf16x8 bk1 = *(const bf16x8*)(Kb + (g * 16 + col) * 72 + 32 + quad * 8);
            zz = __builtin_amdgcn_mfma_f32_16x16x32_bf16(aq0, bk0, zz, 0, 0, 0);
            s[g] = __builtin_amdgcn_mfma_f32_16x16x32_bf16(aq1, bk1, zz, 0, 0, 0);
        }

#pragma unroll
        for (int i = 0; i < 4; ++i) {
#pragma unroll
            for (int g = 0; g < 4; ++g) {
                const float si = val[g] ? (s[g][i] + mval[g]) : -1e30f;
                const float pv = __expf(si);
                lacc[i] += pv;
                Ps[wavei][(quad * 4 + i) * 72 + g * 16 + col] = (bf16)pv;
            }
        }

        const bf16x8 aP0 = *(const bf16x8*)(Ps[wavei] + col * 72 + quad * 8);
        const bf16x8 aP1 = *(const bf16x8*)(Ps[wavei] + col * 72 + 32 + quad * 8);
#pragma unroll
        for (int nt = 0; nt < 4; ++nt) {
            const bf16x8 b0 = *(const bf16x8*)(Vt + (nt * 16 + col) * 72 + quad * 8);
            const bf16x8 b1 = *(const bf16x8*)(Vt + (nt * 16 + col) * 72 + 32 + quad * 8);
            o[nt] = __builtin_amdgcn_mfma_f32_16x16x32_bf16(aP0, b0, o[nt], 0, 0, 0);
            o[nt] = __builtin_amdgcn_mfma_f32_16x16x32_bf16(aP1, b1, o[nt], 0, 0, 0);
        }

        if (more) {
            bf16* KbN = KbS[nxt];
            bf16* VtN = VtS[nxt];
            *(bf16x8*)(KbN + srow * 72 + sd16)     = rk0;
            *(bf16x8*)(KbN + srow * 72 + sd16 + 8) = rk1;
#pragma unroll
            for (int j = 0; j < 8; ++j) {
                bf16 pr[2] = { rv0[j], rv1[j] };
                *(unsigned int*)(VtN + (dg8 + j) * 72 + key0) = *(unsigned int*)pr;
            }
        }
    }

    if (single) {
        // whole window in this block: normalize in-register, write f32 out
#pragma unroll
        for (int i = 0; i < 4; ++i) {
            float rs = lacc[i];
            rs += __shfl_xor(rs, 1);
            rs += __shfl_xor(rs, 2);
            rs += __shfl_xor(rs, 4);
            rs += __shfl_xor(rs, 8);
            const float inv = 1.0f / rs;
            const int rg = b * S_LEN + qb * 16 + quad * 4 + i;
#pragma unroll
            for (int nt = 0; nt < 4; ++nt)
                out[(size_t)rg * D_MODEL + h * HD + nt * 16 + col] = o[nt][i] * inv;
        }
    } else {
#pragma unroll
        for (int i = 0; i < 4; ++i) {
            float rs = lacc[i];
            rs += __shfl_xor(rs, 1);
            rs += __shfl_xor(rs, 2);
            rs += __shfl_xor(rs, 4);
            rs += __shfl_xor(rs, 8);
            const int rg = b * S_LEN + qb * 16 + quad * 4 + i;
            if (col == 0) atomicAdd(L + rg * NH + h, rs);
#pragma unroll
            for (int nt = 0; nt < 4; ++nt)
                atomicAdd(Oacc + (size_t)rg * D_MODEL + h * HD + nt * 16 + col, o[nt][i]);
        }
    }
}

// ---------------------------------------------------------------------------
// Normalize multi-part rows only (rows 832..2047 per batch): out = Oacc / L.
// ---------------------------------------------------------------------------
__global__ __launch_bounds__(256) void normalize_mp(
    const float* __restrict__ Oacc, const float* __restrict__ L,
    float* __restrict__ out)
{
    const int g   = blockIdx.x * 256 + threadIdx.x;
    const int b   = g / (MPROWS * 256);
    const int rem = g % (MPROWS * 256);
    const int row = MPROW0 + (rem >> 8);
    const int c4  = (rem & 255) << 2;
    const int rg  = b * S_LEN + row;
    const float inv = 1.0f / L[rg * NH + (c4 >> 6)];
    const size_t off = (size_t)rg * D_MODEL + c4;
    float4 v = *(const float4*)(Oacc + off);
    v.x *= inv; v.y *= inv; v.z *= inv; v.w *= inv;
    *(float4*)(out + off) = v;
}

// ---------------------------------------------------------------------------
extern "C" void kernel_launch(void* const* d_in, const int* in_sizes, int n_in,
                              void* d_out, int out_size, void* d_ws, size_t ws_size,
                              hipStream_t stream)
{
    const float* x = nullptr; const float* kpm = nullptr;
    const float* Wp[3] = {nullptr, nullptr, nullptr};
    const float* bp[3] = {nullptr, nullptr, nullptr};
    int wn = 0, bn = 0;
    for (int i = 0; i < n_in; ++i) {
        const float* p = (const float*)d_in[i];
        const long s = in_sizes[i];
        if (s == (long)NX)            x = p;
        else if (s == BATCH * S_LEN)  kpm = p;
        else if (s == D_MODEL * D_MODEL && wn < 3) Wp[wn++] = p;
        else if (s == D_MODEL && bn < 3)           bp[bn++] = p;
    }

    // ws: [Q 8MB | K 8MB | V 8MB | O_acc 16MB | L 256KB]
    bf16*  Qb   = (bf16*)d_ws;
    bf16*  Kb   = Qb + NX;
    bf16*  Vb   = Kb + NX;
    float* Oacc = (float*)(Vb + NX);
    float* Lp   = Oacc + NX;
    // d_out doubles as pre-attention scratch: [Xb 8MB | Wt 6MB] (dead after gemm).
    bf16* Xb = (bf16*)d_out;
    bf16* Wt = Xb + NX;
    float* outp = (float*)d_out;

    cvt_all<<<5312, 256, 0, stream>>>(x, Wp[0], Wp[1], Wp[2], Xb, Wt, Oacc, Lp);

    gemm_bt<<<dim3(24, 32), 256, 0, stream>>>(Xb, Wt, bp[0], bp[1], bp[2], Qb);

    sparse_attn_part<<<dim3(54, NH * BATCH), 256, 0, stream>>>(
        Qb, Kb, Vb, kpm, Oacc, Lp, outp);

    normalize_mp<<<(BATCH * MPROWS * 256) / 256, 256, 0, stream>>>(Oacc, Lp, outp);
}